// Round 9
// baseline (177.485 us; speedup 1.0000x reference)
//
#include <hip/hip_runtime.h>
#include <hip/hip_bf16.h>
#include <math.h>

#define B_ 4
#define S_ 2048
#define E_ 256
#define H_ 4
#define D_ 64
#define NROW (B_*S_)      // 8192
#define NCH 4
#define CHK (S_/NCH)      // 512
#define FM 12.0f          // fixed softmax max; |logit| <= ~11.5 since temp>=0.5

typedef __attribute__((ext_vector_type(8))) short short8;   // 8 bf16
typedef __attribute__((ext_vector_type(4))) float floatx4;  // 4 fp32 acc

__device__ __forceinline__ short f2bf(float f){
    union{float f; unsigned u;} x; x.f = f;
    unsigned r = x.u + 0x7fffu + ((x.u>>16)&1u);   // RTNE
    return (short)(r>>16);
}
__device__ __forceinline__ float bf2f(short s){
    union{unsigned u; float f;} x; x.u = ((unsigned)(unsigned short)s)<<16; return x.f;
}
// pack two fp32 -> dword of two bf16 (truncation), 1 v_perm
__device__ __forceinline__ unsigned pk_trunc(float lo, float hi){
    return __builtin_amdgcn_perm(__float_as_uint(hi), __float_as_uint(lo), 0x07060302u);
}

// ---------------- W fp32 [k][n] -> bf16 transposed [n][k] ----------------
__global__ __launch_bounds__(256) void transpose_w(
    const float* __restrict__ W0, const float* __restrict__ W1,
    const float* __restrict__ W2, const float* __restrict__ W3,
    short* __restrict__ T0, short* __restrict__ T1,
    short* __restrict__ T2, short* __restrict__ T3)
{
    const float* W = blockIdx.y==0?W0: blockIdx.y==1?W1: blockIdx.y==2?W2:W3;
    short*       T = blockIdx.y==0?T0: blockIdx.y==1?T1: blockIdx.y==2?T2:T3;
    __shared__ float L[64][65];
    const int t = threadIdx.x;
    const int k0 = (blockIdx.x>>2)*64, n0 = (blockIdx.x&3)*64;
    {
        int r = t>>2, c0 = (t&3)*16;
        const float4* p = (const float4*)(W + (size_t)(k0+r)*E_ + n0 + c0);
        #pragma unroll
        for (int j=0;j<4;++j){
            float4 u = p[j];
            L[r][c0+4*j]=u.x; L[r][c0+4*j+1]=u.y; L[r][c0+4*j+2]=u.z; L[r][c0+4*j+3]=u.w;
        }
    }
    __syncthreads();
    {
        int n = t>>2, kk0 = (t&3)*16;
        short8 o0, o1;
        #pragma unroll
        for(int j=0;j<8;++j) o0[j] = f2bf(L[kk0+j][n]);
        #pragma unroll
        for(int j=0;j<8;++j) o1[j] = f2bf(L[kk0+8+j][n]);
        short* dst = T + (size_t)(n0+n)*E_ + k0 + kk0;
        *(short8*)dst = o0; *(short8*)(dst+8) = o1;
    }
}

// ---------------- QKV MFMA GEMM (R6-proven 2-barrier form), X converted in-stage ----------------
__global__ __launch_bounds__(256) void qkv_gemm(
    const float* __restrict__ X,
    const short* __restrict__ Wtq, const float* __restrict__ bq,
    const short* __restrict__ Wtk, const float* __restrict__ bk,
    const short* __restrict__ Wtv, const float* __restrict__ bv,
    const int* __restrict__ mask,
    const float* __restrict__ explore, const float* __restrict__ exploit,
    short* __restrict__ Q, short* __restrict__ K, short* __restrict__ Vt)
{
    const int z = blockIdx.z;
    const short* Wt   = z==0?Wtq: z==1?Wtk:Wtv;
    const float* bias = z==0?bq:  z==1?bk:bv;

    __shared__ __align__(16) short As[64][72];
    __shared__ __align__(16) short Bs[64][72];

    const int t=threadIdx.x, w=t>>6, lane=t&63, ln=lane&15, quad=lane>>4;
    const int m0 = blockIdx.y*64, n0 = blockIdx.x*64;

    floatx4 acc[4] = {};
    for (int kt=0; kt<E_; kt+=64){
        __syncthreads();
        {
            int r=t>>2, c0=(t&3)*16;
            const float4* pa = (const float4*)(X + (size_t)(m0+r)*E_ + kt + c0);
            short8 s0, s1;
            float4 u;
            u=pa[0]; s0[0]=f2bf(u.x); s0[1]=f2bf(u.y); s0[2]=f2bf(u.z); s0[3]=f2bf(u.w);
            u=pa[1]; s0[4]=f2bf(u.x); s0[5]=f2bf(u.y); s0[6]=f2bf(u.z); s0[7]=f2bf(u.w);
            u=pa[2]; s1[0]=f2bf(u.x); s1[1]=f2bf(u.y); s1[2]=f2bf(u.z); s1[3]=f2bf(u.w);
            u=pa[3]; s1[4]=f2bf(u.x); s1[5]=f2bf(u.y); s1[6]=f2bf(u.z); s1[7]=f2bf(u.w);
            *(short8*)&As[r][c0] = s0; *(short8*)&As[r][c0+8] = s1;
            const uint4* pb = (const uint4*)(Wt + (size_t)(n0+r)*E_ + kt + c0);
            *(uint4*)&Bs[r][c0] = pb[0]; *(uint4*)&Bs[r][c0+8] = pb[1];
        }
        __syncthreads();
        short8 a0 = *(const short8*)&As[w*16+ln][quad*8];
        short8 a1 = *(const short8*)&As[w*16+ln][32+quad*8];
        #pragma unroll
        for (int c=0;c<4;++c){
            short8 b0 = *(const short8*)&Bs[c*16+ln][quad*8];
            short8 b1 = *(const short8*)&Bs[c*16+ln][32+quad*8];
            acc[c] = __builtin_amdgcn_mfma_f32_16x16x32_bf16(a0,b0,acc[c],0,0,0);
            acc[c] = __builtin_amdgcn_mfma_f32_16x16x32_bf16(a1,b1,acc[c],0,0,0);
        }
    }
    if (z==0){
        // fold 1/(8*temp) into Q (before bf16 rounding: error-neutral)
        float tscr[4];
        #pragma unroll
        for(int reg=0;reg<4;++reg){
            int row = m0 + w*16 + quad*4 + reg;    // == b*S + s
            float ex = explore[row], xp = exploit[row];
            float tmp = fminf(fmaxf(1.0f + 0.5f*ex - 0.5f*xp, 0.5f), 2.0f);
            tscr[reg] = mask[row] ? 0.125f : 1.0f/(8.0f*tmp);
        }
        #pragma unroll
        for(int c=0;c<4;++c){
            int colg = n0 + c*16 + ln;
            float bia = bias[colg];
            #pragma unroll
            for(int reg=0;reg<4;++reg){
                int row = m0 + w*16 + quad*4 + reg;
                Q[(size_t)row*E_ + colg] = f2bf((acc[c][reg] + bia)*tscr[reg]);
            }
        }
    } else if (z==1){
        #pragma unroll
        for(int c=0;c<4;++c){
            int colg = n0 + c*16 + ln;
            float bia = bias[colg];
            #pragma unroll
            for(int reg=0;reg<4;++reg){
                int row = m0 + w*16 + quad*4 + reg;
                K[(size_t)row*E_ + colg] = f2bf(acc[c][reg] + bia);
            }
        }
    } else {
        #pragma unroll
        for(int c=0;c<4;++c){
            int colg = n0 + c*16 + ln;
            int hx = colg>>6, d = colg&63;
            float bia = bias[colg];
            #pragma unroll
            for(int reg=0;reg<4;++reg){
                int row = m0 + w*16 + quad*4 + reg;
                int bb = row>>11, s = row&(S_-1);
                Vt[((size_t)((bb*H_+hx)*D_+d))*S_ + s] = f2bf(acc[c][reg] + bia);
            }
        }
    }
}

// ---------------- BARRIER-FREE MFMA flash attention ----------------
// S^T form: K A-frags and V B-frags are contiguous 16B global reads (L1/L2-hot);
// P transposes through per-wave LDS (same-wave ds ordering). No __syncthreads in K-loop.
__global__ __launch_bounds__(256,4) void attn_mfma(
    const short* __restrict__ Qb, const short* __restrict__ Kb, const short* __restrict__ Vtb,
    const int* __restrict__ mask,
    short* __restrict__ OP, float* __restrict__ Lb)
{
    const int bh = blockIdx.z;            // b*H+h
    const int b = bh>>2, h = bh&3;
    const int q0 = blockIdx.x*128;
    const int ck = blockIdx.y, k0 = ck*CHK;
    const int t=threadIdx.x, w=t>>6, lane=t&63, ln=lane&15, quad=lane>>4;

    __shared__ __align__(16) short Ps[4][32][72];  // per-wave P, [q][key]

    // Q B-frags (Q pre-scaled by 1/(8*temp))
    short8 qa[2][2];
    #pragma unroll
    for (int qh=0; qh<2; ++qh){
        const short* qr = Qb + (size_t)(b*S_ + q0 + w*32 + qh*16 + ln)*E_ + h*D_;
        qa[qh][0] = *(const short8*)(qr + quad*8);
        qa[qh][1] = *(const short8*)(qr + 32 + quad*8);
    }

    const short* kbase = Kb + (size_t)(b*S_)*E_ + h*D_;
    const short* vgl   = Vtb + (size_t)bh*D_*S_;
    const int*   mbase = mask + b*S_;

    floatx4 of[2][4] = {};
    float lacc[2] = {0.f, 0.f};

    for (int kt=k0; kt<k0+CHK; kt+=64){
        // QK^T (S^T layout: row=key, col=q) + fixed-max softmax + pack into Ps[q][key]
        #pragma unroll
        for (int c=0;c<4;++c){
            const short* kr = kbase + (size_t)(kt + c*16 + ln)*E_;
            short8 ka0 = *(const short8*)(kr + quad*8);        // A[m=key][k=d 0..31]
            short8 ka1 = *(const short8*)(kr + 32 + quad*8);   // A[m=key][k=d 32..63]
            int4 mk = *(const int4*)(mbase + kt + c*16 + quad*4);
            float mv0 = mk.x ? -1e30f : -FM;
            float mv1 = mk.y ? -1e30f : -FM;
            float mv2 = mk.z ? -1e30f : -FM;
            float mv3 = mk.w ? -1e30f : -FM;
            #pragma unroll
            for (int qh=0; qh<2; ++qh){
                floatx4 s = {};
                s = __builtin_amdgcn_mfma_f32_16x16x32_bf16(ka0, qa[qh][0], s, 0,0,0);
                s = __builtin_amdgcn_mfma_f32_16x16x32_bf16(ka1, qa[qh][1], s, 0,0,0);
                float p0 = __expf(s[0] + mv0);
                float p1 = __expf(s[1] + mv1);
                float p2 = __expf(s[2] + mv2);
                float p3 = __expf(s[3] + mv3);
                lacc[qh] += (p0+p1)+(p2+p3);
                uint2 pw; pw.x = pk_trunc(p0,p1); pw.y = pk_trunc(p2,p3);
                *(uint2*)&Ps[w][qh*16+ln][c*16+quad*4] = pw;
            }
        }

        // PV: P A-frags from per-wave LDS (same-wave dep), V B-frags from global
        #pragma unroll
        for (int half=0; half<2; ++half){
            short8 pa0 = *(const short8*)&Ps[w][ln]   [half*32 + quad*8];
            short8 pa1 = *(const short8*)&Ps[w][16+ln][half*32 + quad*8];
            #pragma unroll
            for (int dc=0; dc<4; ++dc){
                short8 vb = *(const short8*)(vgl + (size_t)(dc*16+ln)*S_ + kt + half*32 + quad*8);
                of[0][dc] = __builtin_amdgcn_mfma_f32_16x16x32_bf16(pa0, vb, of[0][dc], 0,0,0);
                of[1][dc] = __builtin_amdgcn_mfma_f32_16x16x32_bf16(pa1, vb, of[1][dc], 0,0,0);
            }
        }
    }

    #pragma unroll
    for (int qh=0; qh<2; ++qh){
        float l = lacc[qh];
        l += __shfl_xor(l, 16);
        l += __shfl_xor(l, 32);
        #pragma unroll
        for (int dc=0; dc<4; ++dc){
            #pragma unroll
            for (int reg=0; reg<4; ++reg){
                int q = q0 + w*32 + qh*16 + quad*4 + reg;
                OP[((size_t)(ck*16 + bh)*S_ + q)*D_ + dc*16 + ln] = f2bf(of[qh][dc][reg]);
            }
        }
        if (quad==0)
            Lb[(size_t)(ck*16 + bh)*S_ + q0 + w*32 + qh*16 + ln] = l;
    }
}

// ---------------- out GEMM, split-K combine fused into A-stage (simple 2-barrier form) ----------------
__global__ __launch_bounds__(256) void out_gemm(
    const short* __restrict__ OP, const float* __restrict__ Lb,
    const short* __restrict__ Wto, const float* __restrict__ bo,
    const int* __restrict__ mask, float* __restrict__ out)
{
    __shared__ __align__(16) short As[64][72];
    __shared__ __align__(16) short Bs[64][72];
    const int t=threadIdx.x, w=t>>6, lane=t&63, ln=lane&15, quad=lane>>4;
    const int m0 = blockIdx.y*64, n0 = blockIdx.x*64;
    const int r = t>>2, c0 = (t&3)*16;
    const int row = m0 + r, bq = row>>11, s = row&(S_-1);

    floatx4 acc[4] = {};
    for (int kt=0; kt<E_; kt+=64){
        __syncthreads();
        {
            int h = kt>>6, bh_ = bq*H_ + h;
            float osum[16]; float lsum = 0.f;
            #pragma unroll
            for (int j=0;j<16;++j) osum[j] = 0.f;
            #pragma unroll
            for (int cc=0; cc<NCH; ++cc){
                const uint4* p = (const uint4*)(OP + ((size_t)(cc*16 + bh_)*S_ + s)*D_ + c0);
                uint4 u0 = p[0], u1 = p[1];
                const short* sp0 = (const short*)&u0;
                const short* sp1 = (const short*)&u1;
                #pragma unroll
                for (int j=0;j<8;++j){ osum[j] += bf2f(sp0[j]); osum[8+j] += bf2f(sp1[j]); }
                lsum += Lb[(size_t)(cc*16 + bh_)*S_ + s];
            }
            float linv = 1.0f / fmaxf(lsum, 1e-8f);
            short8 s0, s1;
            #pragma unroll
            for (int j=0;j<8;++j){ s0[j] = f2bf(osum[j]*linv); s1[j] = f2bf(osum[8+j]*linv); }
            *(short8*)&As[r][c0] = s0; *(short8*)&As[r][c0+8] = s1;
            const uint4* pb = (const uint4*)(Wto + (size_t)(n0+r)*E_ + kt + c0);
            *(uint4*)&Bs[r][c0] = pb[0]; *(uint4*)&Bs[r][c0+8] = pb[1];
        }
        __syncthreads();
        short8 a0 = *(const short8*)&As[w*16+ln][quad*8];
        short8 a1 = *(const short8*)&As[w*16+ln][32+quad*8];
        #pragma unroll
        for (int c=0;c<4;++c){
            short8 b0 = *(const short8*)&Bs[c*16+ln][quad*8];
            short8 b1 = *(const short8*)&Bs[c*16+ln][32+quad*8];
            acc[c] = __builtin_amdgcn_mfma_f32_16x16x32_bf16(a0,b0,acc[c],0,0,0);
            acc[c] = __builtin_amdgcn_mfma_f32_16x16x32_bf16(a1,b1,acc[c],0,0,0);
        }
    }
    #pragma unroll
    for(int c=0;c<4;++c){
        int colg = n0 + c*16 + ln;
        float bia = bo[colg];
        #pragma unroll
        for(int reg=0;reg<4;++reg){
            int rowg = m0 + w*16 + quad*4 + reg;
            out[(size_t)rowg*E_ + colg] = mask[rowg] ? 0.0f : (acc[c][reg] + bia);
        }
    }
}

extern "C" void kernel_launch(void* const* d_in, const int* in_sizes, int n_in,
                              void* d_out, int out_size, void* d_ws, size_t ws_size,
                              hipStream_t stream) {
    const float* his     = (const float*)d_in[0];
    const int*   mask    = (const int*)d_in[1];
    const float* explore = (const float*)d_in[2];
    const float* exploit = (const float*)d_in[3];
    const float* Wq = (const float*)d_in[4];
    const float* bq = (const float*)d_in[5];
    const float* Wk = (const float*)d_in[6];
    const float* bk = (const float*)d_in[7];
    const float* Wv = (const float*)d_in[8];
    const float* bv = (const float*)d_in[9];
    const float* Wo = (const float*)d_in[10];
    const float* bo = (const float*)d_in[11];

    char* ws = (char*)d_ws;
    const size_t NE2 = (size_t)NROW * E_ * 2;              // 4 MB (bf16)
    short* Wtq  = (short*)(ws);                    ws += E_*E_*2;
    short* Wtk  = (short*)(ws);                    ws += E_*E_*2;
    short* Wtv  = (short*)(ws);                    ws += E_*E_*2;
    short* Wto  = (short*)(ws);                    ws += E_*E_*2;
    short* Qb   = (short*)(ws);                    ws += NE2;
    short* Kb   = (short*)(ws);                    ws += NE2;
    short* Vtb  = (short*)(ws);                    ws += NE2;
    short* OP   = (short*)(ws);                    ws += (size_t)NCH*B_*H_*S_*D_*2;  // 16 MB
    float* Lb   = (float*)(ws);                    ws += (size_t)NCH*B_*H_*S_*4;     // 512 KB

    transpose_w<<<dim3(16,4), 256, 0, stream>>>(Wq, Wk, Wv, Wo, Wtq, Wtk, Wtv, Wto);

    qkv_gemm<<<dim3(E_/64, NROW/64, 3), 256, 0, stream>>>(
        his, Wtq, bq, Wtk, bk, Wtv, bv, mask, explore, exploit, Qb, Kb, Vtb);

    attn_mfma<<<dim3(S_/128, NCH, B_*H_), 256, 0, stream>>>(
        Qb, Kb, Vtb, mask, OP, Lb);

    out_gemm<<<dim3(E_/64, NROW/64), 256, 0, stream>>>(OP, Lb, Wto, bo, mask, (float*)d_out);
}

// Round 10
// 151.117 us; speedup vs baseline: 1.1745x; 1.1745x over previous
//
#include <hip/hip_runtime.h>
#include <hip/hip_bf16.h>
#include <math.h>

#define B_ 4
#define S_ 2048
#define E_ 256
#define H_ 4
#define D_ 64
#define NROW (B_*S_)      // 8192
#define NCH 4
#define CHK (S_/NCH)      // 512
#define FM 12.0f          // fixed softmax max; |logit| <= ~11.5 since temp>=0.5

typedef __attribute__((ext_vector_type(8))) short short8;   // 8 bf16
typedef __attribute__((ext_vector_type(4))) float floatx4;  // 4 fp32 acc

__device__ __forceinline__ short f2bf(float f){
    union{float f; unsigned u;} x; x.f = f;
    unsigned r = x.u + 0x7fffu + ((x.u>>16)&1u);   // RTNE
    return (short)(r>>16);
}
__device__ __forceinline__ float bf2f(short s){
    union{unsigned u; float f;} x; x.u = ((unsigned)(unsigned short)s)<<16; return x.f;
}
// pack two fp32 -> dword of two bf16 (truncation), 1 v_perm
__device__ __forceinline__ unsigned pk_trunc(float lo, float hi){
    return __builtin_amdgcn_perm(__float_as_uint(hi), __float_as_uint(lo), 0x07060302u);
}

// ---------------- W fp32 [k][n] -> bf16 transposed [n][k] ----------------
__global__ __launch_bounds__(256) void transpose_w(
    const float* __restrict__ W0, const float* __restrict__ W1,
    const float* __restrict__ W2, const float* __restrict__ W3,
    short* __restrict__ T0, short* __restrict__ T1,
    short* __restrict__ T2, short* __restrict__ T3)
{
    const float* W = blockIdx.y==0?W0: blockIdx.y==1?W1: blockIdx.y==2?W2:W3;
    short*       T = blockIdx.y==0?T0: blockIdx.y==1?T1: blockIdx.y==2?T2:T3;
    __shared__ float L[64][65];
    const int t = threadIdx.x;
    const int k0 = (blockIdx.x>>2)*64, n0 = (blockIdx.x&3)*64;
    {
        int r = t>>2, c0 = (t&3)*16;
        const float4* p = (const float4*)(W + (size_t)(k0+r)*E_ + n0 + c0);
        #pragma unroll
        for (int j=0;j<4;++j){
            float4 u = p[j];
            L[r][c0+4*j]=u.x; L[r][c0+4*j+1]=u.y; L[r][c0+4*j+2]=u.z; L[r][c0+4*j+3]=u.w;
        }
    }
    __syncthreads();
    {
        int n = t>>2, kk0 = (t&3)*16;
        short8 o0, o1;
        #pragma unroll
        for(int j=0;j<8;++j) o0[j] = f2bf(L[kk0+j][n]);
        #pragma unroll
        for(int j=0;j<8;++j) o1[j] = f2bf(L[kk0+8+j][n]);
        short* dst = T + (size_t)(n0+n)*E_ + k0 + kk0;
        *(short8*)dst = o0; *(short8*)(dst+8) = o1;
    }
}

// ---------------- fused QKV MFMA GEMM: X staged once, 3 W tiles, 3 accumulator sets ----------------
__global__ __launch_bounds__(256) void qkv_gemm(
    const float* __restrict__ X,
    const short* __restrict__ Wtq, const float* __restrict__ bq,
    const short* __restrict__ Wtk, const float* __restrict__ bk,
    const short* __restrict__ Wtv, const float* __restrict__ bv,
    const int* __restrict__ mask,
    const float* __restrict__ explore, const float* __restrict__ exploit,
    short* __restrict__ Q, short* __restrict__ K, short* __restrict__ Vt)
{
    __shared__ __align__(16) short As[64][72];
    __shared__ __align__(16) short BsQ[64][72];
    __shared__ __align__(16) short BsK[64][72];
    __shared__ __align__(16) short BsV[64][72];

    const int t=threadIdx.x, w=t>>6, lane=t&63, ln=lane&15, quad=lane>>4;
    const int m0 = blockIdx.y*64, n0 = blockIdx.x*64;

    floatx4 aq[4] = {}, ak[4] = {}, av[4] = {};
    for (int kt=0; kt<E_; kt+=64){
        __syncthreads();
        {
            int r=t>>2, c0=(t&3)*16;
            const float4* pa = (const float4*)(X + (size_t)(m0+r)*E_ + kt + c0);
            short8 s0, s1;
            float4 u;
            u=pa[0]; s0[0]=f2bf(u.x); s0[1]=f2bf(u.y); s0[2]=f2bf(u.z); s0[3]=f2bf(u.w);
            u=pa[1]; s0[4]=f2bf(u.x); s0[5]=f2bf(u.y); s0[6]=f2bf(u.z); s0[7]=f2bf(u.w);
            u=pa[2]; s1[0]=f2bf(u.x); s1[1]=f2bf(u.y); s1[2]=f2bf(u.z); s1[3]=f2bf(u.w);
            u=pa[3]; s1[4]=f2bf(u.x); s1[5]=f2bf(u.y); s1[6]=f2bf(u.z); s1[7]=f2bf(u.w);
            *(short8*)&As[r][c0] = s0; *(short8*)&As[r][c0+8] = s1;
            size_t woff = (size_t)(n0+r)*E_ + kt + c0;
            const uint4* pq = (const uint4*)(Wtq + woff);
            *(uint4*)&BsQ[r][c0] = pq[0]; *(uint4*)&BsQ[r][c0+8] = pq[1];
            const uint4* pk = (const uint4*)(Wtk + woff);
            *(uint4*)&BsK[r][c0] = pk[0]; *(uint4*)&BsK[r][c0+8] = pk[1];
            const uint4* pv = (const uint4*)(Wtv + woff);
            *(uint4*)&BsV[r][c0] = pv[0]; *(uint4*)&BsV[r][c0+8] = pv[1];
        }
        __syncthreads();
        short8 a0 = *(const short8*)&As[w*16+ln][quad*8];
        short8 a1 = *(const short8*)&As[w*16+ln][32+quad*8];
        #pragma unroll
        for (int c=0;c<4;++c){
            short8 b0 = *(const short8*)&BsQ[c*16+ln][quad*8];
            short8 b1 = *(const short8*)&BsQ[c*16+ln][32+quad*8];
            aq[c] = __builtin_amdgcn_mfma_f32_16x16x32_bf16(a0,b0,aq[c],0,0,0);
            aq[c] = __builtin_amdgcn_mfma_f32_16x16x32_bf16(a1,b1,aq[c],0,0,0);
            b0 = *(const short8*)&BsK[c*16+ln][quad*8];
            b1 = *(const short8*)&BsK[c*16+ln][32+quad*8];
            ak[c] = __builtin_amdgcn_mfma_f32_16x16x32_bf16(a0,b0,ak[c],0,0,0);
            ak[c] = __builtin_amdgcn_mfma_f32_16x16x32_bf16(a1,b1,ak[c],0,0,0);
            b0 = *(const short8*)&BsV[c*16+ln][quad*8];
            b1 = *(const short8*)&BsV[c*16+ln][32+quad*8];
            av[c] = __builtin_amdgcn_mfma_f32_16x16x32_bf16(a0,b0,av[c],0,0,0);
            av[c] = __builtin_amdgcn_mfma_f32_16x16x32_bf16(a1,b1,av[c],0,0,0);
        }
    }
    {   // Q epilogue: fold 1/(8*temp) into Q (before bf16 rounding: error-neutral)
        float tscr[4];
        #pragma unroll
        for(int reg=0;reg<4;++reg){
            int row = m0 + w*16 + quad*4 + reg;    // == b*S + s
            float ex = explore[row], xp = exploit[row];
            float tmp = fminf(fmaxf(1.0f + 0.5f*ex - 0.5f*xp, 0.5f), 2.0f);
            tscr[reg] = mask[row] ? 0.125f : 1.0f/(8.0f*tmp);
        }
        #pragma unroll
        for(int c=0;c<4;++c){
            int colg = n0 + c*16 + ln;
            float bia = bq[colg];
            #pragma unroll
            for(int reg=0;reg<4;++reg){
                int row = m0 + w*16 + quad*4 + reg;
                Q[(size_t)row*E_ + colg] = f2bf((aq[c][reg] + bia)*tscr[reg]);
            }
        }
    }
    #pragma unroll
    for(int c=0;c<4;++c){   // K epilogue
        int colg = n0 + c*16 + ln;
        float bia = bk[colg];
        #pragma unroll
        for(int reg=0;reg<4;++reg){
            int row = m0 + w*16 + quad*4 + reg;
            K[(size_t)row*E_ + colg] = f2bf(ak[c][reg] + bia);
        }
    }
    #pragma unroll
    for(int c=0;c<4;++c){   // V epilogue (transposed per head)
        int colg = n0 + c*16 + ln;
        int hx = colg>>6, d = colg&63;
        float bia = bv[colg];
        #pragma unroll
        for(int reg=0;reg<4;++reg){
            int row = m0 + w*16 + quad*4 + reg;
            int bb = row>>11, s = row&(S_-1);
            Vt[((size_t)((bb*H_+hx)*D_+d))*S_ + s] = f2bf(av[c][reg] + bia);
        }
    }
}

// ---------------- MFMA flash attention: R6 LDS-staged loop + S^T QK^T + uint2 P-writes ----------------
__global__ __launch_bounds__(256) void attn_mfma(
    const short* __restrict__ Qb, const short* __restrict__ Kb, const short* __restrict__ Vtb,
    const int* __restrict__ mask,
    short* __restrict__ OP, float* __restrict__ Lb)
{
    const int bh = blockIdx.z;            // b*H+h
    const int b = bh>>2, h = bh&3;
    const int q0 = blockIdx.x*64;
    const int ck = blockIdx.y, k0 = ck*CHK;
    const int t=threadIdx.x, w=t>>6, lane=t&63, ln=lane&15, quad=lane>>4;

    __shared__ __align__(16) short Ks[64][72];     // [key][d]
    __shared__ __align__(16) short Vs[64][72];     // [d][key]
    __shared__ __align__(16) short Ps[4][16][72];  // per-wave P, [q][key]
    __shared__ float mv[64];                        // (masked? -1e30 : 0) - FM

    // Q B-frags (Q pre-scaled by 1/(8*temp)); wave w owns q rows q0+w*16+ln
    const short* qr = Qb + (size_t)(b*S_ + q0 + w*16 + ln)*E_ + h*D_;
    short8 qb0 = *(const short8*)(qr + quad*8);
    short8 qb1 = *(const short8*)(qr + 32 + quad*8);

    const int sr = t>>2, sc0 = (t&3)*16;
    const short* kgl = Kb + (size_t)(b*S_ + sr)*E_ + h*D_ + sc0;
    const short* vgl = Vtb + ((size_t)(bh*D_ + sr))*S_ + sc0;

    floatx4 of[4] = {};
    float lacc = 0.0f;

    for (int kt=k0; kt<k0+CHK; kt+=64){
        __syncthreads();
        {
            const uint4* gk = (const uint4*)(kgl + (size_t)kt*E_);
            *(uint4*)&Ks[sr][sc0] = gk[0]; *(uint4*)&Ks[sr][sc0+8] = gk[1];
            const uint4* gv = (const uint4*)(vgl + kt);
            *(uint4*)&Vs[sr][sc0] = gv[0]; *(uint4*)&Vs[sr][sc0+8] = gv[1];
        }
        if (t<64) mv[t] = (mask[b*S_+kt+t] ? -1e30f : 0.0f) - FM;
        __syncthreads();

        // QK^T in S^T layout (A=K: m=key, B=Q: n=q) + fixed-max softmax + uint2 pack to Ps[q][key]
        #pragma unroll
        for (int c=0;c<4;++c){
            short8 ka0 = *(const short8*)&Ks[c*16+ln][quad*8];
            short8 ka1 = *(const short8*)&Ks[c*16+ln][32+quad*8];
            float4 mvv = *(const float4*)&mv[c*16+quad*4];
            floatx4 s = {};
            s = __builtin_amdgcn_mfma_f32_16x16x32_bf16(ka0, qb0, s, 0,0,0);
            s = __builtin_amdgcn_mfma_f32_16x16x32_bf16(ka1, qb1, s, 0,0,0);
            float p0 = __expf(s[0] + mvv.x);
            float p1 = __expf(s[1] + mvv.y);
            float p2 = __expf(s[2] + mvv.z);
            float p3 = __expf(s[3] + mvv.w);
            lacc += (p0+p1)+(p2+p3);              // partial over keys for q=ln (this quad's 4 keys)
            uint2 pw; pw.x = pk_trunc(p0,p1); pw.y = pk_trunc(p2,p3);
            *(uint2*)&Ps[w][ln][c*16+quad*4] = pw;
        }

        // PV: P A-frags + V B-frags from LDS (per-wave Ps: same-wave ds ordering, no extra barrier)
        #pragma unroll
        for (int half=0; half<2; ++half){
            short8 pa = *(const short8*)&Ps[w][ln][half*32 + quad*8];
            #pragma unroll
            for (int dc=0; dc<4; ++dc){
                short8 vb = *(const short8*)&Vs[dc*16+ln][half*32 + quad*8];
                of[dc] = __builtin_amdgcn_mfma_f32_16x16x32_bf16(pa, vb, of[dc], 0,0,0);
            }
        }
    }

    // reduce l over quads (lacc is per (q=ln, quad))
    float l = lacc;
    l += __shfl_xor(l, 16);
    l += __shfl_xor(l, 32);
    #pragma unroll
    for (int dc=0; dc<4; ++dc){
        #pragma unroll
        for (int reg=0; reg<4; ++reg){
            int q = q0 + w*16 + quad*4 + reg;
            OP[((size_t)(ck*16 + bh)*S_ + q)*D_ + dc*16 + ln] = f2bf(of[dc][reg]);
        }
    }
    if (quad==0)
        Lb[(size_t)(ck*16 + bh)*S_ + q0 + w*16 + ln] = l;
}

// ---------------- out GEMM, split-K combine fused into A-stage ----------------
__global__ __launch_bounds__(256) void out_gemm(
    const short* __restrict__ OP, const float* __restrict__ Lb,
    const short* __restrict__ Wto, const float* __restrict__ bo,
    const int* __restrict__ mask, float* __restrict__ out)
{
    __shared__ __align__(16) short As[64][72];
    __shared__ __align__(16) short Bs[64][72];
    const int t=threadIdx.x, w=t>>6, lane=t&63, ln=lane&15, quad=lane>>4;
    const int m0 = blockIdx.y*64, n0 = blockIdx.x*64;
    const int r = t>>2, c0 = (t&3)*16;
    const int row = m0 + r, bq = row>>11, s = row&(S_-1);

    floatx4 acc[4] = {};
    for (int kt=0; kt<E_; kt+=64){
        __syncthreads();
        {
            int h = kt>>6, bh_ = bq*H_ + h;
            float osum[16]; float lsum = 0.f;
            #pragma unroll
            for (int j=0;j<16;++j) osum[j] = 0.f;
            #pragma unroll
            for (int cc=0; cc<NCH; ++cc){
                const uint4* p = (const uint4*)(OP + ((size_t)(cc*16 + bh_)*S_ + s)*D_ + c0);
                uint4 u0 = p[0], u1 = p[1];
                const short* sp0 = (const short*)&u0;
                const short* sp1 = (const short*)&u1;
                #pragma unroll
                for (int j=0;j<8;++j){ osum[j] += bf2f(sp0[j]); osum[8+j] += bf2f(sp1[j]); }
                lsum += Lb[(size_t)(cc*16 + bh_)*S_ + s];
            }
            float linv = 1.0f / fmaxf(lsum, 1e-8f);
            short8 s0, s1;
            #pragma unroll
            for (int j=0;j<8;++j){ s0[j] = f2bf(osum[j]*linv); s1[j] = f2bf(osum[8+j]*linv); }
            *(short8*)&As[r][c0] = s0; *(short8*)&As[r][c0+8] = s1;
            const uint4* pb = (const uint4*)(Wto + (size_t)(n0+r)*E_ + kt + c0);
            *(uint4*)&Bs[r][c0] = pb[0]; *(uint4*)&Bs[r][c0+8] = pb[1];
        }
        __syncthreads();
        short8 a0 = *(const short8*)&As[w*16+ln][quad*8];
        short8 a1 = *(const short8*)&As[w*16+ln][32+quad*8];
        #pragma unroll
        for (int c=0;c<4;++c){
            short8 b0 = *(const short8*)&Bs[c*16+ln][quad*8];
            short8 b1 = *(const short8*)&Bs[c*16+ln][32+quad*8];
            acc[c] = __builtin_amdgcn_mfma_f32_16x16x32_bf16(a0,b0,acc[c],0,0,0);
            acc[c] = __builtin_amdgcn_mfma_f32_16x16x32_bf16(a1,b1,acc[c],0,0,0);
        }
    }
    #pragma unroll
    for(int c=0;c<4;++c){
        int colg = n0 + c*16 + ln;
        float bia = bo[colg];
        #pragma unroll
        for(int reg=0;reg<4;++reg){
            int rowg = m0 + w*16 + quad*4 + reg;
            out[(size_t)rowg*E_ + colg] = mask[rowg] ? 0.0f : (acc[c][reg] + bia);
        }
    }
}

extern "C" void kernel_launch(void* const* d_in, const int* in_sizes, int n_in,
                              void* d_out, int out_size, void* d_ws, size_t ws_size,
                              hipStream_t stream) {
    const float* his     = (const float*)d_in[0];
    const int*   mask    = (const int*)d_in[1];
    const float* explore = (const float*)d_in[2];
    const float* exploit = (const float*)d_in[3];
    const float* Wq = (const float*)d_in[4];
    const float* bq = (const float*)d_in[5];
    const float* Wk = (const float*)d_in[6];
    const float* bk = (const float*)d_in[7];
    const float* Wv = (const float*)d_in[8];
    const float* bv = (const float*)d_in[9];
    const float* Wo = (const float*)d_in[10];
    const float* bo = (const float*)d_in[11];

    char* ws = (char*)d_ws;
    const size_t NE2 = (size_t)NROW * E_ * 2;              // 4 MB (bf16)
    short* Wtq  = (short*)(ws);                    ws += E_*E_*2;
    short* Wtk  = (short*)(ws);                    ws += E_*E_*2;
    short* Wtv  = (short*)(ws);                    ws += E_*E_*2;
    short* Wto  = (short*)(ws);                    ws += E_*E_*2;
    short* Qb   = (short*)(ws);                    ws += NE2;
    short* Kb   = (short*)(ws);                    ws += NE2;
    short* Vtb  = (short*)(ws);                    ws += NE2;
    short* OP   = (short*)(ws);                    ws += (size_t)NCH*B_*H_*S_*D_*2;  // 16 MB
    float* Lb   = (float*)(ws);                    ws += (size_t)NCH*B_*H_*S_*4;     // 512 KB

    transpose_w<<<dim3(16,4), 256, 0, stream>>>(Wq, Wk, Wv, Wo, Wtq, Wtk, Wtv, Wto);

    qkv_gemm<<<dim3(E_/64, NROW/64), 256, 0, stream>>>(
        his, Wtq, bq, Wtk, bk, Wtv, bv, mask, explore, exploit, Qb, Kb, Vtb);

    attn_mfma<<<dim3(S_/64, NCH, B_*H_), 256, 0, stream>>>(
        Qb, Kb, Vtb, mask, OP, Lb);

    out_gemm<<<dim3(E_/64, NROW/64), 256, 0, stream>>>(OP, Lb, Wto, bo, mask, (float*)d_out);
}

// Round 11
// 149.801 us; speedup vs baseline: 1.1848x; 1.0088x over previous
//
#include <hip/hip_runtime.h>
#include <hip/hip_bf16.h>
#include <math.h>

#define B_ 4
#define S_ 2048
#define E_ 256
#define H_ 4
#define D_ 64
#define NROW (B_*S_)      // 8192
#define NCH 8
#define CHK (S_/NCH)      // 256
#define FM 12.0f          // fixed softmax max; |logit| <= ~11.5 since temp>=0.5

typedef __attribute__((ext_vector_type(8))) short short8;   // 8 bf16
typedef __attribute__((ext_vector_type(4))) float floatx4;  // 4 fp32 acc

__device__ __forceinline__ short f2bf(float f){
    union{float f; unsigned u;} x; x.f = f;
    unsigned r = x.u + 0x7fffu + ((x.u>>16)&1u);   // RTNE
    return (short)(r>>16);
}
__device__ __forceinline__ float bf2f(short s){
    union{unsigned u; float f;} x; x.u = ((unsigned)(unsigned short)s)<<16; return x.f;
}
// pack two fp32 -> dword of two bf16 (truncation), 1 v_perm
__device__ __forceinline__ unsigned pk_trunc(float lo, float hi){
    return __builtin_amdgcn_perm(__float_as_uint(hi), __float_as_uint(lo), 0x07060302u);
}

// ---------------- W fp32 [k][n] -> bf16 transposed [n][k] ----------------
__global__ __launch_bounds__(256) void transpose_w(
    const float* __restrict__ W0, const float* __restrict__ W1,
    const float* __restrict__ W2, const float* __restrict__ W3,
    short* __restrict__ T0, short* __restrict__ T1,
    short* __restrict__ T2, short* __restrict__ T3)
{
    const float* W = blockIdx.y==0?W0: blockIdx.y==1?W1: blockIdx.y==2?W2:W3;
    short*       T = blockIdx.y==0?T0: blockIdx.y==1?T1: blockIdx.y==2?T2:T3;
    __shared__ float L[64][65];
    const int t = threadIdx.x;
    const int k0 = (blockIdx.x>>2)*64, n0 = (blockIdx.x&3)*64;
    {
        int r = t>>2, c0 = (t&3)*16;
        const float4* p = (const float4*)(W + (size_t)(k0+r)*E_ + n0 + c0);
        #pragma unroll
        for (int j=0;j<4;++j){
            float4 u = p[j];
            L[r][c0+4*j]=u.x; L[r][c0+4*j+1]=u.y; L[r][c0+4*j+2]=u.z; L[r][c0+4*j+3]=u.w;
        }
    }
    __syncthreads();
    {
        int n = t>>2, kk0 = (t&3)*16;
        short8 o0, o1;
        #pragma unroll
        for(int j=0;j<8;++j) o0[j] = f2bf(L[kk0+j][n]);
        #pragma unroll
        for(int j=0;j<8;++j) o1[j] = f2bf(L[kk0+8+j][n]);
        short* dst = T + (size_t)(n0+n)*E_ + k0 + kk0;
        *(short8*)dst = o0; *(short8*)(dst+8) = o1;
    }
}

// ---------------- QKV MFMA GEMM (3 z-slices, proven R6/R9 form), X converted in-stage ----------------
__global__ __launch_bounds__(256) void qkv_gemm(
    const float* __restrict__ X,
    const short* __restrict__ Wtq, const float* __restrict__ bq,
    const short* __restrict__ Wtk, const float* __restrict__ bk,
    const short* __restrict__ Wtv, const float* __restrict__ bv,
    const int* __restrict__ mask,
    const float* __restrict__ explore, const float* __restrict__ exploit,
    short* __restrict__ Q, short* __restrict__ K, short* __restrict__ Vt)
{
    const int z = blockIdx.z;
    const short* Wt   = z==0?Wtq: z==1?Wtk:Wtv;
    const float* bias = z==0?bq:  z==1?bk:bv;

    __shared__ __align__(16) short As[64][72];
    __shared__ __align__(16) short Bs[64][72];

    const int t=threadIdx.x, w=t>>6, lane=t&63, ln=lane&15, quad=lane>>4;
    const int m0 = blockIdx.y*64, n0 = blockIdx.x*64;

    floatx4 acc[4] = {};
    for (int kt=0; kt<E_; kt+=64){
        __syncthreads();
        {
            int r=t>>2, c0=(t&3)*16;
            const float4* pa = (const float4*)(X + (size_t)(m0+r)*E_ + kt + c0);
            short8 s0, s1;
            float4 u;
            u=pa[0]; s0[0]=f2bf(u.x); s0[1]=f2bf(u.y); s0[2]=f2bf(u.z); s0[3]=f2bf(u.w);
            u=pa[1]; s0[4]=f2bf(u.x); s0[5]=f2bf(u.y); s0[6]=f2bf(u.z); s0[7]=f2bf(u.w);
            u=pa[2]; s1[0]=f2bf(u.x); s1[1]=f2bf(u.y); s1[2]=f2bf(u.z); s1[3]=f2bf(u.w);
            u=pa[3]; s1[4]=f2bf(u.x); s1[5]=f2bf(u.y); s1[6]=f2bf(u.z); s1[7]=f2bf(u.w);
            *(short8*)&As[r][c0] = s0; *(short8*)&As[r][c0+8] = s1;
            const uint4* pb = (const uint4*)(Wt + (size_t)(n0+r)*E_ + kt + c0);
            *(uint4*)&Bs[r][c0] = pb[0]; *(uint4*)&Bs[r][c0+8] = pb[1];
        }
        __syncthreads();
        short8 a0 = *(const short8*)&As[w*16+ln][quad*8];
        short8 a1 = *(const short8*)&As[w*16+ln][32+quad*8];
        #pragma unroll
        for (int c=0;c<4;++c){
            short8 b0 = *(const short8*)&Bs[c*16+ln][quad*8];
            short8 b1 = *(const short8*)&Bs[c*16+ln][32+quad*8];
            acc[c] = __builtin_amdgcn_mfma_f32_16x16x32_bf16(a0,b0,acc[c],0,0,0);
            acc[c] = __builtin_amdgcn_mfma_f32_16x16x32_bf16(a1,b1,acc[c],0,0,0);
        }
    }
    if (z==0){
        // fold 1/(8*temp) into Q (before bf16 rounding: error-neutral)
        float tscr[4];
        #pragma unroll
        for(int reg=0;reg<4;++reg){
            int row = m0 + w*16 + quad*4 + reg;    // == b*S + s
            float ex = explore[row], xp = exploit[row];
            float tmp = fminf(fmaxf(1.0f + 0.5f*ex - 0.5f*xp, 0.5f), 2.0f);
            tscr[reg] = mask[row] ? 0.125f : 1.0f/(8.0f*tmp);
        }
        #pragma unroll
        for(int c=0;c<4;++c){
            int colg = n0 + c*16 + ln;
            float bia = bias[colg];
            #pragma unroll
            for(int reg=0;reg<4;++reg){
                int row = m0 + w*16 + quad*4 + reg;
                Q[(size_t)row*E_ + colg] = f2bf((acc[c][reg] + bia)*tscr[reg]);
            }
        }
    } else if (z==1){
        #pragma unroll
        for(int c=0;c<4;++c){
            int colg = n0 + c*16 + ln;
            float bia = bias[colg];
            #pragma unroll
            for(int reg=0;reg<4;++reg){
                int row = m0 + w*16 + quad*4 + reg;
                K[(size_t)row*E_ + colg] = f2bf(acc[c][reg] + bia);
            }
        }
    } else {
        #pragma unroll
        for(int c=0;c<4;++c){
            int colg = n0 + c*16 + ln;
            int hx = colg>>6, d = colg&63;
            float bia = bias[colg];
            #pragma unroll
            for(int reg=0;reg<4;++reg){
                int row = m0 + w*16 + quad*4 + reg;
                int bb = row>>11, s = row&(S_-1);
                Vt[((size_t)((bb*H_+hx)*D_+d))*S_ + s] = f2bf(acc[c][reg] + bia);
            }
        }
    }
}

// ---------------- MFMA flash attention: LDS-staged, S^T QK^T, uint2 P-writes, NCH=8 ----------------
__global__ __launch_bounds__(256) void attn_mfma(
    const short* __restrict__ Qb, const short* __restrict__ Kb, const short* __restrict__ Vtb,
    const int* __restrict__ mask,
    short* __restrict__ OP, float* __restrict__ Lb)
{
    const int bh = blockIdx.z;            // b*H+h
    const int b = bh>>2, h = bh&3;
    const int q0 = blockIdx.x*64;
    const int ck = blockIdx.y, k0 = ck*CHK;
    const int t=threadIdx.x, w=t>>6, lane=t&63, ln=lane&15, quad=lane>>4;

    __shared__ __align__(16) short Ks[64][72];     // [key][d]
    __shared__ __align__(16) short Vs[64][72];     // [d][key]
    __shared__ __align__(16) short Ps[4][16][72];  // per-wave P, [q][key]
    __shared__ float mvAll[CHK];                    // (masked? -1e30 : 0) - FM, whole chunk

    // hoisted mask preload (once per block, outside the k-loop chain)
    if (t < CHK) mvAll[t] = (mask[b*S_ + k0 + t] ? -1e30f : 0.0f) - FM;

    // Q B-frags (Q pre-scaled by 1/(8*temp)); wave w owns q rows q0+w*16+ln
    const short* qr = Qb + (size_t)(b*S_ + q0 + w*16 + ln)*E_ + h*D_;
    short8 qb0 = *(const short8*)(qr + quad*8);
    short8 qb1 = *(const short8*)(qr + 32 + quad*8);

    const int sr = t>>2, sc0 = (t&3)*16;
    const short* kgl = Kb + (size_t)(b*S_ + sr)*E_ + h*D_ + sc0;
    const short* vgl = Vtb + ((size_t)(bh*D_ + sr))*S_ + sc0;

    floatx4 of[4] = {};
    float lacc = 0.0f;

    for (int kt=k0; kt<k0+CHK; kt+=64){
        __syncthreads();
        {
            const uint4* gk = (const uint4*)(kgl + (size_t)kt*E_);
            *(uint4*)&Ks[sr][sc0] = gk[0]; *(uint4*)&Ks[sr][sc0+8] = gk[1];
            const uint4* gv = (const uint4*)(vgl + kt);
            *(uint4*)&Vs[sr][sc0] = gv[0]; *(uint4*)&Vs[sr][sc0+8] = gv[1];
        }
        __syncthreads();

        // QK^T in S^T layout (A=K: m=key, B=Q: n=q) + fixed-max softmax + uint2 pack to Ps[q][key]
        #pragma unroll
        for (int c=0;c<4;++c){
            short8 ka0 = *(const short8*)&Ks[c*16+ln][quad*8];
            short8 ka1 = *(const short8*)&Ks[c*16+ln][32+quad*8];
            float4 mvv = *(const float4*)&mvAll[(kt-k0) + c*16+quad*4];
            floatx4 s = {};
            s = __builtin_amdgcn_mfma_f32_16x16x32_bf16(ka0, qb0, s, 0,0,0);
            s = __builtin_amdgcn_mfma_f32_16x16x32_bf16(ka1, qb1, s, 0,0,0);
            float p0 = __expf(s[0] + mvv.x);
            float p1 = __expf(s[1] + mvv.y);
            float p2 = __expf(s[2] + mvv.z);
            float p3 = __expf(s[3] + mvv.w);
            lacc += (p0+p1)+(p2+p3);              // partial over keys for q=ln (this quad's 4 keys)
            uint2 pw; pw.x = pk_trunc(p0,p1); pw.y = pk_trunc(p2,p3);
            *(uint2*)&Ps[w][ln][c*16+quad*4] = pw;
        }

        // PV: P A-frags + V B-frags from LDS (per-wave Ps: same-wave ds ordering, no extra barrier)
        #pragma unroll
        for (int half=0; half<2; ++half){
            short8 pa = *(const short8*)&Ps[w][ln][half*32 + quad*8];
            #pragma unroll
            for (int dc=0; dc<4; ++dc){
                short8 vb = *(const short8*)&Vs[dc*16+ln][half*32 + quad*8];
                of[dc] = __builtin_amdgcn_mfma_f32_16x16x32_bf16(pa, vb, of[dc], 0,0,0);
            }
        }
    }

    // reduce l over quads (lacc is per (q=ln, quad))
    float l = lacc;
    l += __shfl_xor(l, 16);
    l += __shfl_xor(l, 32);
    #pragma unroll
    for (int dc=0; dc<4; ++dc){
        #pragma unroll
        for (int reg=0; reg<4; ++reg){
            int q = q0 + w*16 + quad*4 + reg;
            OP[((size_t)(ck*16 + bh)*S_ + q)*D_ + dc*16 + ln] = f2bf(of[dc][reg]);
        }
    }
    if (quad==0)
        Lb[(size_t)(ck*16 + bh)*S_ + q0 + w*16 + ln] = l;
}

// ---------------- combine split-K partials -> bf16 ctx [row][e], vectorized ----------------
__global__ __launch_bounds__(256) void combine(
    const short* __restrict__ OP, const float* __restrict__ Lb, short* __restrict__ CTXb)
{
    int gid = blockIdx.x*256 + threadIdx.x;   // 1024 blocks; one 8-elem group per thread
    int e8 = gid & 31;                        // 32 groups of 8 per row
    int row = gid >> 5;
    int e = e8*8;
    int hh = e >> 6, d0 = e & 63;
    int bb = row >> 11, s = row & (S_-1);
    int bh = bb*H_ + hh;

    float osum[8] = {};
    float lsum = 0.f;
    #pragma unroll
    for (int c=0;c<NCH;++c){
        uint4 u = *(const uint4*)(OP + ((size_t)(c*16 + bh)*S_ + s)*D_ + d0);
        const short* sp = (const short*)&u;
        #pragma unroll
        for (int j=0;j<8;++j) osum[j] += bf2f(sp[j]);
        lsum += Lb[(size_t)(c*16 + bh)*S_ + s];
    }
    float linv = 1.0f / fmaxf(lsum, 1e-8f);
    short8 o;
    #pragma unroll
    for (int j=0;j<8;++j) o[j] = f2bf(osum[j]*linv);
    *(short8*)(CTXb + (size_t)row*E_ + e) = o;
}

// ---------------- output MFMA GEMM + bias + mask-zero, fp32 out (simple R6 form) ----------------
__global__ __launch_bounds__(256) void out_gemm(
    const short* __restrict__ Ab, const short* __restrict__ Wto, const float* __restrict__ bo,
    const int* __restrict__ mask, float* __restrict__ out)
{
    __shared__ __align__(16) short As[64][72];
    __shared__ __align__(16) short Bs[64][72];
    const int t=threadIdx.x, w=t>>6, lane=t&63, ln=lane&15, quad=lane>>4;
    const int m0 = blockIdx.y*64, n0 = blockIdx.x*64;
    floatx4 acc[4] = {};
    for (int kt=0; kt<E_; kt+=64){
        __syncthreads();
        {
            int r=t>>2, c0=(t&3)*16;
            const uint4* pa = (const uint4*)(Ab + (size_t)(m0+r)*E_ + kt + c0);
            *(uint4*)&As[r][c0] = pa[0]; *(uint4*)&As[r][c0+8] = pa[1];
            const uint4* pb = (const uint4*)(Wto + (size_t)(n0+r)*E_ + kt + c0);
            *(uint4*)&Bs[r][c0] = pb[0]; *(uint4*)&Bs[r][c0+8] = pb[1];
        }
        __syncthreads();
        short8 a0 = *(const short8*)&As[w*16+ln][quad*8];
        short8 a1 = *(const short8*)&As[w*16+ln][32+quad*8];
        #pragma unroll
        for (int c=0;c<4;++c){
            short8 b0 = *(const short8*)&Bs[c*16+ln][quad*8];
            short8 b1 = *(const short8*)&Bs[c*16+ln][32+quad*8];
            acc[c] = __builtin_amdgcn_mfma_f32_16x16x32_bf16(a0,b0,acc[c],0,0,0);
            acc[c] = __builtin_amdgcn_mfma_f32_16x16x32_bf16(a1,b1,acc[c],0,0,0);
        }
    }
    #pragma unroll
    for(int c=0;c<4;++c){
        int colg = n0 + c*16 + ln;
        float bia = bo[colg];
        #pragma unroll
        for(int reg=0;reg<4;++reg){
            int row = m0 + w*16 + quad*4 + reg;
            out[(size_t)row*E_ + colg] = mask[row] ? 0.0f : (acc[c][reg] + bia);
        }
    }
}

extern "C" void kernel_launch(void* const* d_in, const int* in_sizes, int n_in,
                              void* d_out, int out_size, void* d_ws, size_t ws_size,
                              hipStream_t stream) {
    const float* his     = (const float*)d_in[0];
    const int*   mask    = (const int*)d_in[1];
    const float* explore = (const float*)d_in[2];
    const float* exploit = (const float*)d_in[3];
    const float* Wq = (const float*)d_in[4];
    const float* bq = (const float*)d_in[5];
    const float* Wk = (const float*)d_in[6];
    const float* bk = (const float*)d_in[7];
    const float* Wv = (const float*)d_in[8];
    const float* bv = (const float*)d_in[9];
    const float* Wo = (const float*)d_in[10];
    const float* bo = (const float*)d_in[11];

    char* ws = (char*)d_ws;
    const size_t NE2 = (size_t)NROW * E_ * 2;              // 4 MB (bf16)
    short* Wtq  = (short*)(ws);                    ws += E_*E_*2;
    short* Wtk  = (short*)(ws);                    ws += E_*E_*2;
    short* Wtv  = (short*)(ws);                    ws += E_*E_*2;
    short* Wto  = (short*)(ws);                    ws += E_*E_*2;
    short* Qb   = (short*)(ws);                    ws += NE2;
    short* Kb   = (short*)(ws);                    ws += NE2;
    short* Vtb  = (short*)(ws);                    ws += NE2;
    short* OP   = (short*)(ws);                    ws += (size_t)NCH*B_*H_*S_*D_*2;  // 32 MB
    float* Lb   = (float*)(ws);                    ws += (size_t)NCH*B_*H_*S_*4;     // 1 MB
    short* CTXb = Qb;    // alias: Qb dead after attn (stream-ordered)

    transpose_w<<<dim3(16,4), 256, 0, stream>>>(Wq, Wk, Wv, Wo, Wtq, Wtk, Wtv, Wto);

    qkv_gemm<<<dim3(E_/64, NROW/64, 3), 256, 0, stream>>>(
        his, Wtq, bq, Wtk, bk, Wtv, bv, mask, explore, exploit, Qb, Kb, Vtb);

    attn_mfma<<<dim3(S_/64, NCH, B_*H_), 256, 0, stream>>>(
        Qb, Kb, Vtb, mask, OP, Lb);

    combine<<<1024, 256, 0, stream>>>(OP, Lb, CTXb);

    out_gemm<<<dim3(E_/64, NROW/64), 256, 0, stream>>>(CTXb, Wto, bo, mask, (float*)d_out);
}